// Round 2
// baseline (217.407 us; speedup 1.0000x reference)
//
#include <hip/hip_runtime.h>
#include <hip/hip_bf16.h>

// Head: out[b,t,h] = softmax_causal( (x@Wq)(x@Wk)^T * 6^-0.5 ) @ (x@Wv)
// B=512 T=128 C=384 H=64.
// v2: barrier-free QKV phase (W pre-transposed to bf16 in ws by wt_conv),
//     512-thread blocks (8 waves), 48 KB LDS, launch_bounds(512,4).

#define B_ 512
#define T_ 128
#define C_ 384
#define H_ 64

typedef __bf16 bf16;
typedef __attribute__((ext_vector_type(8))) __bf16 bf16x8;
typedef __attribute__((ext_vector_type(4))) __bf16 bf16x4;
typedef __attribute__((ext_vector_type(4))) float f32x4;

// ---- pre-kernel: Wt[n][k] = W_j[k][h], n=j*64+h, bf16, k-contiguous ----
__global__ void wt_conv(const float* __restrict__ Wq,
                        const float* __restrict__ Wk,
                        const float* __restrict__ Wv,
                        bf16* __restrict__ Wt)
{
    int idx = blockIdx.x * 256 + threadIdx.x;   // [0, 9216)
    int n  = idx / 48;                          // 0..191
    int k0 = (idx - n * 48) * 8;                // 0..376 step 8
    int j = n >> 6, h = n & 63;
    const float* W = (j == 0) ? Wq : (j == 1) ? Wk : Wv;
    bf16x8 v;
#pragma unroll
    for (int r = 0; r < 8; ++r) v[r] = (bf16)W[(k0 + r) * 64 + h];
    *(bf16x8*)&Wt[n * 384 + k0] = v;
}

// LDS (bf16 elems): Qs [0,8192) 128x64 swz | Ks [8192,16384) | Vts [16384,24576) 64x128 swz
// Ps 128x128 swz aliases [0,16384) after barrier. Total 49152 B -> 3 blocks/CU by LDS.
__launch_bounds__(512, 4)
__global__ void head_fused(const float* __restrict__ x,
                           const bf16* __restrict__ Wt,
                           float* __restrict__ out)
{
    __shared__ bf16 lds[24576];
    bf16* Qs  = lds;
    bf16* Ks  = lds + 8192;
    bf16* Vts = lds + 16384;
    bf16* Ps  = lds;

    const int tid  = threadIdx.x;
    const int w    = tid >> 6;     // wave 0..7  (= its m-tile)
    const int lane = tid & 63;
    const int lm   = lane & 15;
    const int quad = lane >> 4;
    const int b    = blockIdx.x;

    const float* xb = x + (size_t)b * (T_ * C_);
    const int mrow = 16 * w + lm;  // this lane's A-row / Q-row (0..127)

    // ================= Phase 1: QKV = x[b] @ Wt^T (no barriers) =================
    f32x4 acc[12];
#pragma unroll
    for (int t = 0; t < 12; ++t) acc[t] = (f32x4){0.f, 0.f, 0.f, 0.f};

#pragma unroll 1
    for (int kc = 0; kc < 12; ++kc) {
        const float4* xp = (const float4*)(xb + mrow * C_ + kc * 32 + quad * 8);
        float4 p0 = xp[0], p1 = xp[1];
        bf16x8 afr = {(bf16)p0.x, (bf16)p0.y, (bf16)p0.z, (bf16)p0.w,
                      (bf16)p1.x, (bf16)p1.y, (bf16)p1.z, (bf16)p1.w};
#pragma unroll
        for (int tn = 0; tn < 12; ++tn) {
            bf16x8 bfr = *(const bf16x8*)&Wt[(16 * tn + lm) * 384 + kc * 32 + quad * 8];
            acc[tn] = __builtin_amdgcn_mfma_f32_16x16x32_bf16(afr, bfr, acc[tn], 0, 0, 0);
        }
    }

    // epilogue: Q,K row-major [t][h]; V transposed [h][t]; swizzled bf16
#pragma unroll
    for (int tn = 0; tn < 12; ++tn) {
        int h  = (16 * tn + lm) & 63;
        int m0 = 16 * w + quad * 4;
        if (tn >= 8) {
            bf16x4 v4 = {(bf16)acc[tn][0], (bf16)acc[tn][1],
                         (bf16)acc[tn][2], (bf16)acc[tn][3]};
            int pc = (m0 & 7) | ((((m0 >> 3) ^ (h & 15)) & 15) << 3);
            *(bf16x4*)&Vts[h * 128 + pc] = v4;
        } else {
            bf16* dst = (tn < 4) ? Qs : Ks;
#pragma unroll
            for (int r = 0; r < 4; ++r) {
                int m = m0 + r;
                int pc = (h & 7) | ((((h >> 3) ^ (m & 7)) & 7) << 3);
                dst[m * 64 + pc] = (bf16)acc[tn][r];
            }
        }
    }
    __syncthreads();

    // ================= Phase 2: attention (wave w owns m-tile w) =================
    const float SCALE = 0.40824829046386307f;  // 6^-0.5
    const int tm = w;

    f32x4 sacc[8];
#pragma unroll
    for (int t = 0; t < 8; ++t) sacc[t] = (f32x4){0.f, 0.f, 0.f, 0.f};

    bf16x8 qa[2];
#pragma unroll
    for (int ks = 0; ks < 2; ++ks) {
        int phys = ((ks * 4 + quad) ^ (mrow & 7)) & 7;
        qa[ks] = *(const bf16x8*)&Qs[mrow * 64 + phys * 8];
    }
#pragma unroll
    for (int tn = 0; tn < 8; ++tn) {
        if (tn <= tm) {
            int nrow = 16 * tn + lm;
#pragma unroll
            for (int ks = 0; ks < 2; ++ks) {
                int phys = ((ks * 4 + quad) ^ (nrow & 7)) & 7;
                bf16x8 kb = *(const bf16x8*)&Ks[nrow * 64 + phys * 8];
                sacc[tn] = __builtin_amdgcn_mfma_f32_16x16x32_bf16(qa[ks], kb, sacc[tn], 0, 0, 0);
            }
        }
    }

    // softmax in registers; row's 16 cols live in one 16-lane group
#pragma unroll
    for (int r = 0; r < 4; ++r) {
        int m = 16 * tm + quad * 4 + r;
        float mx = -1e30f;
#pragma unroll
        for (int tn = 0; tn < 8; ++tn) {
            if (tn <= tm) {
                int n = 16 * tn + lm;
                float v = (n <= m) ? sacc[tn][r] * SCALE : -1e30f;
                sacc[tn][r] = v;
                mx = fmaxf(mx, v);
            }
        }
#pragma unroll
        for (int off = 1; off < 16; off <<= 1) mx = fmaxf(mx, __shfl_xor(mx, off, 16));
        float sum = 0.f;
#pragma unroll
        for (int tn = 0; tn < 8; ++tn) {
            if (tn <= tm) {
                float e = __expf(sacc[tn][r] - mx);
                sacc[tn][r] = e;
                sum += e;
            }
        }
#pragma unroll
        for (int off = 1; off < 16; off <<= 1) sum += __shfl_xor(sum, off, 16);
        float inv = 1.f / sum;
#pragma unroll
        for (int tn = 0; tn < 8; ++tn) {
            if (tn <= tm) sacc[tn][r] *= inv;
        }
    }

    __syncthreads();  // all waves done reading Qs/Ks; Ps aliases them

    // write P (own rows only -> no barrier needed before PV)
#pragma unroll
    for (int tn = 0; tn < 8; ++tn) {
        if (tn <= tm) {
            int n = 16 * tn + lm;
#pragma unroll
            for (int r = 0; r < 4; ++r) {
                int m = 16 * tm + quad * 4 + r;
                int pc = (n & 7) | ((((n >> 3) ^ (m & 15)) & 15) << 3);
                Ps[m * 128 + pc] = (bf16)sacc[tn][r];
            }
        }
    }
    if ((tm & 1) == 0) {  // zero half-covered k-tile
        int m = 16 * tm + lm;
        int c0 = 16 * (tm + 1) + quad * 4;
        int pc = (c0 & 7) | ((((c0 >> 3) ^ (m & 15)) & 15) << 3);
        *(bf16x4*)&Ps[m * 128 + pc] = (bf16x4){(bf16)0.f, (bf16)0.f, (bf16)0.f, (bf16)0.f};
    }

    // O = P @ V
    f32x4 oacc[4];
#pragma unroll
    for (int t = 0; t < 4; ++t) oacc[t] = (f32x4){0.f, 0.f, 0.f, 0.f};

    const int nks = (tm + 2) >> 1;  // wave-uniform
    for (int ks = 0; ks < nks; ++ks) {
        int unit = ks * 4 + quad;
        int phys = (unit ^ (mrow & 15)) & 15;
        bf16x8 pa = *(const bf16x8*)&Ps[mrow * 128 + phys * 8];
#pragma unroll
        for (int th = 0; th < 4; ++th) {
            int hrow = 16 * th + lm;
            int ph2 = (unit ^ (hrow & 15)) & 15;
            bf16x8 vb = *(const bf16x8*)&Vts[hrow * 128 + ph2 * 8];
            oacc[th] = __builtin_amdgcn_mfma_f32_16x16x32_bf16(pa, vb, oacc[th], 0, 0, 0);
        }
    }

    // store O fp32 [b][t][h]
    float* ob = out + (size_t)b * (T_ * H_);
#pragma unroll
    for (int th = 0; th < 4; ++th) {
        int h = 16 * th + lm;
#pragma unroll
        for (int r = 0; r < 4; ++r) {
            int m = 16 * tm + quad * 4 + r;
            ob[m * 64 + h] = oacc[th][r];
        }
    }
}

extern "C" void kernel_launch(void* const* d_in, const int* in_sizes, int n_in,
                              void* d_out, int out_size, void* d_ws, size_t ws_size,
                              hipStream_t stream) {
    const float* x  = (const float*)d_in[0];
    const float* Wq = (const float*)d_in[1];
    const float* Wk = (const float*)d_in[2];
    const float* Wv = (const float*)d_in[3];
    float* o  = (float*)d_out;
    bf16* Wt  = (bf16*)d_ws;   // 192*384*2 = 147456 B
    wt_conv<<<dim3(36), dim3(256), 0, stream>>>(Wq, Wk, Wv, Wt);
    head_fused<<<dim3(B_), dim3(512), 0, stream>>>(x, Wt, o);
}

// Round 3
// 191.915 us; speedup vs baseline: 1.1328x; 1.1328x over previous
//
#include <hip/hip_runtime.h>
#include <hip/hip_bf16.h>

// Head: out[b,t,h] = softmax_causal( (x@Wq)(x@Wk)^T * 6^-0.5 ) @ (x@Wv)
// B=512 T=128 C=384 H=64.
// v3: barrier-free QKV phase (Wt bf16 pre-transposed in ws), 256-thread blocks,
//     2 m-tiles/wave, depth-2 x register prefetch, launch_bounds(256,2) so the
//     96-float accumulator file NEVER spills (round-2 lesson: (512,4) -> 128-reg
//     cap -> scratch spill -> 103us).

#define B_ 512
#define T_ 128
#define C_ 384
#define H_ 64

typedef __bf16 bf16;
typedef __attribute__((ext_vector_type(8))) __bf16 bf16x8;
typedef __attribute__((ext_vector_type(4))) __bf16 bf16x4;
typedef __attribute__((ext_vector_type(4))) float f32x4;

// ---- pre-kernel: Wt[n][k] = W_j[k][h], n=j*64+h, bf16, k-contiguous ----
__global__ void wt_conv(const float* __restrict__ Wq,
                        const float* __restrict__ Wk,
                        const float* __restrict__ Wv,
                        bf16* __restrict__ Wt)
{
    int idx = blockIdx.x * 256 + threadIdx.x;   // [0, 9216)
    int n  = idx / 48;                          // 0..191
    int k0 = (idx - n * 48) * 8;                // 0..376 step 8
    int j = n >> 6, h = n & 63;
    const float* W = (j == 0) ? Wq : (j == 1) ? Wk : Wv;
    bf16x8 v;
#pragma unroll
    for (int r = 0; r < 8; ++r) v[r] = (bf16)W[(k0 + r) * 64 + h];
    *(bf16x8*)&Wt[n * 384 + k0] = v;
}

// LDS (bf16 elems): Qs [0,8192) 128x64 swz | Ks [8192,16384) | Vts [16384,24576)
// Ps 128x128 swz aliases [0,16384). Total 49152 B.
__launch_bounds__(256, 2)
__global__ void head_fused(const float* __restrict__ x,
                           const bf16* __restrict__ Wt,
                           float* __restrict__ out)
{
    __shared__ bf16 lds[24576];
    bf16* Qs  = lds;
    bf16* Ks  = lds + 8192;
    bf16* Vts = lds + 16384;
    bf16* Ps  = lds;

    const int tid  = threadIdx.x;
    const int w    = tid >> 6;     // wave 0..3
    const int lane = tid & 63;
    const int lm   = lane & 15;
    const int quad = lane >> 4;
    const int b    = blockIdx.x;

    const float* xb = x + (size_t)b * (T_ * C_);

    // ================= Phase 1: QKV = x[b] @ Wt^T (no barriers) =================
    // wave w owns m-tiles {2w, 2w+1} (rows 32w..32w+31)
    f32x4 acc[2][12];
#pragma unroll
    for (int i = 0; i < 2; ++i)
#pragma unroll
        for (int t = 0; t < 12; ++t) acc[i][t] = (f32x4){0.f, 0.f, 0.f, 0.f};

    const float* xr0 = xb + (32 * w + lm) * C_ + quad * 8;
    const float* xr1 = xb + (32 * w + 16 + lm) * C_ + quad * 8;

    float4 xbuf[2][2][2];  // [parity][mtile][half] — static after unroll-2
    xbuf[0][0][0] = ((const float4*)xr0)[0];
    xbuf[0][0][1] = ((const float4*)xr0)[1];
    xbuf[0][1][0] = ((const float4*)xr1)[0];
    xbuf[0][1][1] = ((const float4*)xr1)[1];

#pragma unroll 2
    for (int kc = 0; kc < 12; ++kc) {
        const int cb = kc & 1;
        if (kc < 11) {  // prefetch next kc (uniform branch)
            const float4* n0 = (const float4*)(xr0 + (kc + 1) * 32);
            const float4* n1 = (const float4*)(xr1 + (kc + 1) * 32);
            xbuf[cb ^ 1][0][0] = n0[0];
            xbuf[cb ^ 1][0][1] = n0[1];
            xbuf[cb ^ 1][1][0] = n1[0];
            xbuf[cb ^ 1][1][1] = n1[1];
        }
        bf16x8 afr[2];
#pragma unroll
        for (int i = 0; i < 2; ++i) {
            float4 p0 = xbuf[cb][i][0], p1 = xbuf[cb][i][1];
            afr[i] = (bf16x8){(bf16)p0.x, (bf16)p0.y, (bf16)p0.z, (bf16)p0.w,
                              (bf16)p1.x, (bf16)p1.y, (bf16)p1.z, (bf16)p1.w};
        }
#pragma unroll
        for (int tn = 0; tn < 12; ++tn) {
            bf16x8 bfr = *(const bf16x8*)&Wt[(16 * tn + lm) * 384 + kc * 32 + quad * 8];
            acc[0][tn] = __builtin_amdgcn_mfma_f32_16x16x32_bf16(afr[0], bfr, acc[0][tn], 0, 0, 0);
            acc[1][tn] = __builtin_amdgcn_mfma_f32_16x16x32_bf16(afr[1], bfr, acc[1][tn], 0, 0, 0);
        }
    }

    // epilogue: Q,K row-major [t][h]; V transposed [h][t]; swizzled bf16
#pragma unroll
    for (int i = 0; i < 2; ++i) {
#pragma unroll
        for (int tn = 0; tn < 12; ++tn) {
            int h  = (16 * tn + lm) & 63;
            int m0 = 32 * w + 16 * i + quad * 4;
            if (tn >= 8) {
                bf16x4 v4 = {(bf16)acc[i][tn][0], (bf16)acc[i][tn][1],
                             (bf16)acc[i][tn][2], (bf16)acc[i][tn][3]};
                int pc = (m0 & 7) | ((((m0 >> 3) ^ (h & 15)) & 15) << 3);
                *(bf16x4*)&Vts[h * 128 + pc] = v4;
            } else {
                bf16* dst = (tn < 4) ? Qs : Ks;
#pragma unroll
                for (int r = 0; r < 4; ++r) {
                    int m = m0 + r;
                    int pc = (h & 7) | ((((h >> 3) ^ (m & 7)) & 7) << 3);
                    dst[m * 64 + pc] = (bf16)acc[i][tn][r];
                }
            }
        }
    }
    __syncthreads();

    // ================= Phase 2: attention =================
    const float SCALE = 0.40824829046386307f;  // 6^-0.5
    const int tmg0 = w, tmg1 = 7 - w;          // 9 S-tiles per wave, balanced

    f32x4 sacc[2][8];
#pragma unroll
    for (int i = 0; i < 2; ++i)
#pragma unroll
        for (int t = 0; t < 8; ++t) sacc[i][t] = (f32x4){0.f, 0.f, 0.f, 0.f};

#pragma unroll
    for (int i = 0; i < 2; ++i) {
        const int tm = i ? tmg1 : tmg0;
        const int mr = 16 * tm + lm;
        bf16x8 qa[2];
#pragma unroll
        for (int ks = 0; ks < 2; ++ks) {
            int phys = ((ks * 4 + quad) ^ (mr & 7)) & 7;
            qa[ks] = *(const bf16x8*)&Qs[mr * 64 + phys * 8];
        }
#pragma unroll
        for (int tn = 0; tn < 8; ++tn) {
            if (tn <= tm) {
                int nrow = 16 * tn + lm;
#pragma unroll
                for (int ks = 0; ks < 2; ++ks) {
                    int phys = ((ks * 4 + quad) ^ (nrow & 7)) & 7;
                    bf16x8 kb = *(const bf16x8*)&Ks[nrow * 64 + phys * 8];
                    sacc[i][tn] =
                        __builtin_amdgcn_mfma_f32_16x16x32_bf16(qa[ks], kb, sacc[i][tn], 0, 0, 0);
                }
            }
        }
    }

    // softmax in registers; a row's 16 cols live in one 16-lane group
#pragma unroll
    for (int i = 0; i < 2; ++i) {
        const int tm = i ? tmg1 : tmg0;
#pragma unroll
        for (int r = 0; r < 4; ++r) {
            int m = 16 * tm + quad * 4 + r;
            float mx = -1e30f;
#pragma unroll
            for (int tn = 0; tn < 8; ++tn) {
                if (tn <= tm) {
                    int n = 16 * tn + lm;
                    float v = (n <= m) ? sacc[i][tn][r] * SCALE : -1e30f;
                    sacc[i][tn][r] = v;
                    mx = fmaxf(mx, v);
                }
            }
#pragma unroll
            for (int off = 1; off < 16; off <<= 1) mx = fmaxf(mx, __shfl_xor(mx, off, 16));
            float sum = 0.f;
#pragma unroll
            for (int tn = 0; tn < 8; ++tn) {
                if (tn <= tm) {
                    float e = __expf(sacc[i][tn][r] - mx);
                    sacc[i][tn][r] = e;
                    sum += e;
                }
            }
#pragma unroll
            for (int off = 1; off < 16; off <<= 1) sum += __shfl_xor(sum, off, 16);
            float inv = 1.f / sum;
#pragma unroll
            for (int tn = 0; tn < 8; ++tn) {
                if (tn <= tm) sacc[i][tn][r] *= inv;
            }
        }
    }

    __syncthreads();  // all waves done reading Qs/Ks; Ps aliases them

    // write P (own rows only)
#pragma unroll
    for (int i = 0; i < 2; ++i) {
        const int tm = i ? tmg1 : tmg0;
#pragma unroll
        for (int tn = 0; tn < 8; ++tn) {
            if (tn <= tm) {
                int n = 16 * tn + lm;
#pragma unroll
                for (int r = 0; r < 4; ++r) {
                    int m = 16 * tm + quad * 4 + r;
                    int pc = (n & 7) | ((((n >> 3) ^ (m & 15)) & 15) << 3);
                    Ps[m * 128 + pc] = (bf16)sacc[i][tn][r];
                }
            }
        }
        if ((tm & 1) == 0) {  // zero half-covered k-tile
            int m = 16 * tm + lm;
            int c0 = 16 * (tm + 1) + quad * 4;
            int pc = (c0 & 7) | ((((c0 >> 3) ^ (m & 15)) & 15) << 3);
            *(bf16x4*)&Ps[m * 128 + pc] = (bf16x4){(bf16)0.f, (bf16)0.f, (bf16)0.f, (bf16)0.f};
        }
    }

    // O = P @ V
    f32x4 oacc[2][4];
#pragma unroll
    for (int i = 0; i < 2; ++i)
#pragma unroll
        for (int t = 0; t < 4; ++t) oacc[i][t] = (f32x4){0.f, 0.f, 0.f, 0.f};

#pragma unroll
    for (int i = 0; i < 2; ++i) {
        const int tm = i ? tmg1 : tmg0;
        const int mr = 16 * tm + lm;
        const int nks = (tm + 2) >> 1;  // wave-uniform
        for (int ks = 0; ks < nks; ++ks) {
            int unit = ks * 4 + quad;
            int phys = (unit ^ (mr & 15)) & 15;
            bf16x8 pa = *(const bf16x8*)&Ps[mr * 128 + phys * 8];
#pragma unroll
            for (int th = 0; th < 4; ++th) {
                int hrow = 16 * th + lm;
                int ph2 = (unit ^ (hrow & 15)) & 15;
                bf16x8 vb = *(const bf16x8*)&Vts[hrow * 128 + ph2 * 8];
                oacc[i][th] =
                    __builtin_amdgcn_mfma_f32_16x16x32_bf16(pa, vb, oacc[i][th], 0, 0, 0);
            }
        }
    }

    // store O fp32 [b][t][h]
    float* ob = out + (size_t)b * (T_ * H_);
#pragma unroll
    for (int i = 0; i < 2; ++i) {
        const int tm = i ? tmg1 : tmg0;
#pragma unroll
        for (int th = 0; th < 4; ++th) {
            int h = 16 * th + lm;
#pragma unroll
            for (int r = 0; r < 4; ++r) {
                int m = 16 * tm + quad * 4 + r;
                ob[m * 64 + h] = oacc[i][th][r];
            }
        }
    }
}

extern "C" void kernel_launch(void* const* d_in, const int* in_sizes, int n_in,
                              void* d_out, int out_size, void* d_ws, size_t ws_size,
                              hipStream_t stream) {
    const float* x  = (const float*)d_in[0];
    const float* Wq = (const float*)d_in[1];
    const float* Wk = (const float*)d_in[2];
    const float* Wv = (const float*)d_in[3];
    float* o = (float*)d_out;
    bf16* Wt = (bf16*)d_ws;   // 192*384*2 = 147456 B
    wt_conv<<<dim3(36), dim3(256), 0, stream>>>(Wq, Wk, Wv, Wt);
    head_fused<<<dim3(B_), dim3(256), 0, stream>>>(x, Wt, o);
}

// Round 6
// 189.159 us; speedup vs baseline: 1.1493x; 1.0146x over previous
//
#include <hip/hip_runtime.h>
#include <hip/hip_bf16.h>

// Head: out[b,t,h] = softmax_causal( (x@Wq)(x@Wk)^T * 6^-0.5 ) @ (x@Wv)
// B=512 T=128 C=384 H=64.
// v6: grid 1024 (2 blocks/b, 64 q-rows each, K/V duplicated) to break the
//     512-block occupancy cap (rounds 1-3: 2 blocks/CU was the wall).
//     LDS 40960 B; W chunks staged via regs + ds_write_b128 double-buffered
//     (global_load_lds builtin removed — v4/v5 crashed with it, v1-v3 without
//     it passed). Softmax without max-pass. launch_bounds(256,3): cap ~168
//     regs, est 125 live -> no spill (round-2 lesson).

#define B_ 512
#define T_ 128
#define C_ 384
#define H_ 64

typedef __bf16 bf16;
typedef __attribute__((ext_vector_type(8))) __bf16 bf16x8;
typedef __attribute__((ext_vector_type(4))) __bf16 bf16x4;
typedef __attribute__((ext_vector_type(4))) float f32x4;

// ---- pre-kernel: Wt[n][k] = W_j[k][h], n=j*64+h, bf16, k-contiguous ----
__global__ void wt_conv(const float* __restrict__ Wq,
                        const float* __restrict__ Wk,
                        const float* __restrict__ Wv,
                        bf16* __restrict__ Wt)
{
    int idx = blockIdx.x * 256 + threadIdx.x;   // [0, 9216)
    int n  = idx / 48;                          // 0..191
    int k0 = (idx - n * 48) * 8;                // 0..376 step 8
    int j = n >> 6, h = n & 63;
    const float* W = (j == 0) ? Wq : (j == 1) ? Wk : Wv;
    bf16x8 v;
#pragma unroll
    for (int r = 0; r < 8; ++r) v[r] = (bf16)W[(k0 + r) * 64 + h];
    *(bf16x8*)&Wt[n * 384 + k0] = v;
}

// LDS (bf16 elems), total 20480 elems = 40960 B:
//   Qh  [0,4096)       64x64 swz, LOCAL q-rows of this half
//   Ks  [4096,12288)   128x64 swz, global t rows
//   Vts [12288,20480)  64x128 swz (h, global t)
//   Wb0 [0,7680) / Wb1 [7680,15360): 192x40 (pad 8) W-chunk double buffer —
//       aliases Qh/Ks/Vts front; dead before epilogue (barrier-separated)
//   Ps  [4096,12288)   64x128 swz, LOCAL rows — aliases Ks after softmax barrier
__launch_bounds__(256, 3)
__global__ void head_fused(const float* __restrict__ x,
                           const bf16* __restrict__ Wt,
                           float* __restrict__ out)
{
    __shared__ bf16 lds[20480];
    bf16* Qh  = lds;
    bf16* Ks  = lds + 4096;
    bf16* Vts = lds + 12288;
    bf16* Ps  = lds + 4096;
    bf16* Wb0 = lds;
    bf16* Wb1 = lds + 7680;

    const int tid  = threadIdx.x;
    const int w    = tid >> 6;     // wave 0..3
    const int lane = tid & 63;
    const int lm   = lane & 15;
    const int quad = lane >> 4;
    const int blk  = blockIdx.x;   // 0..1023
    const int b    = blk >> 1;
    const int half = blk & 1;

    const float* xb = x + (size_t)b * (T_ * C_);

    // ================= Phase 1: QKV (wave w: KV m-tiles {w, w+4}; Q m-tile w of own half)
    f32x4 accKV[2][8];   // [m-tile i: rows 16(w+4i)][n-tile: n=64+16tn]  (K then V)
    f32x4 accQ[8 - 4];   // n-tile 0..3 (Q), A-rows = own half's rows
#pragma unroll
    for (int i = 0; i < 2; ++i)
#pragma unroll
        for (int t = 0; t < 8; ++t) accKV[i][t] = (f32x4){0.f, 0.f, 0.f, 0.f};
#pragma unroll
    for (int t = 0; t < 4; ++t) accQ[t] = (f32x4){0.f, 0.f, 0.f, 0.f};

    // staging slots: s = tid + 256*j (j<3): row = s>>2 in [0,192), col8 = (s&3)*8
    bf16x8 stg[3];
#pragma unroll
    for (int j = 0; j < 3; ++j) {
        int s = tid + 256 * j, row = s >> 2, c8 = (s & 3) * 8;
        stg[j] = *(const bf16x8*)&Wt[row * 384 + c8];
    }
#pragma unroll
    for (int j = 0; j < 3; ++j) {
        int s = tid + 256 * j, row = s >> 2, c8 = (s & 3) * 8;
        *(bf16x8*)&Wb0[row * 40 + c8] = stg[j];
    }
    __syncthreads();

    const float* xr0 = xb + (16 * w + lm) * C_ + quad * 8;        // rows 0..63
    const float* xr1 = xb + (64 + 16 * w + lm) * C_ + quad * 8;   // rows 64..127

#pragma unroll 2
    for (int kc = 0; kc < 12; ++kc) {
        bf16* cur = (kc & 1) ? Wb1 : Wb0;
        bf16* nxt = (kc & 1) ? Wb0 : Wb1;
        if (kc < 11) {  // issue next-chunk global loads early
#pragma unroll
            for (int j = 0; j < 3; ++j) {
                int s = tid + 256 * j, row = s >> 2, c8 = (s & 3) * 8;
                stg[j] = *(const bf16x8*)&Wt[row * 384 + (kc + 1) * 32 + c8];
            }
        }
        float4 a0 = ((const float4*)(xr0 + kc * 32))[0];
        float4 a1 = ((const float4*)(xr0 + kc * 32))[1];
        float4 c0 = ((const float4*)(xr1 + kc * 32))[0];
        float4 c1 = ((const float4*)(xr1 + kc * 32))[1];
        bf16x8 afr0 = {(bf16)a0.x, (bf16)a0.y, (bf16)a0.z, (bf16)a0.w,
                       (bf16)a1.x, (bf16)a1.y, (bf16)a1.z, (bf16)a1.w};
        bf16x8 afr1 = {(bf16)c0.x, (bf16)c0.y, (bf16)c0.z, (bf16)c0.w,
                       (bf16)c1.x, (bf16)c1.y, (bf16)c1.z, (bf16)c1.w};
#pragma unroll
        for (int tn = 0; tn < 8; ++tn) {  // n = 64+16tn (K,V columns)
            bf16x8 bfr = *(const bf16x8*)&cur[(64 + 16 * tn + lm) * 40 + quad * 8];
            accKV[0][tn] = __builtin_amdgcn_mfma_f32_16x16x32_bf16(afr0, bfr, accKV[0][tn], 0, 0, 0);
            accKV[1][tn] = __builtin_amdgcn_mfma_f32_16x16x32_bf16(afr1, bfr, accKV[1][tn], 0, 0, 0);
        }
        bf16x8 afq = half ? afr1 : afr0;  // Q rows = own half's rows
#pragma unroll
        for (int tn = 0; tn < 4; ++tn) {  // n = 16tn (Q columns)
            bf16x8 bfr = *(const bf16x8*)&cur[(16 * tn + lm) * 40 + quad * 8];
            accQ[tn] = __builtin_amdgcn_mfma_f32_16x16x32_bf16(afq, bfr, accQ[tn], 0, 0, 0);
        }
        if (kc < 11) {
#pragma unroll
            for (int j = 0; j < 3; ++j) {
                int s = tid + 256 * j, row = s >> 2, c8 = (s & 3) * 8;
                *(bf16x8*)&nxt[row * 40 + c8] = stg[j];
            }
        }
        __syncthreads();  // nxt visible; all waves done reading cur
    }
    // Wb lifetime over. Epilogue writes Qh/Ks/Vts.

#pragma unroll
    for (int i = 0; i < 2; ++i) {
        int t0 = 16 * (w + 4 * i) + quad * 4;  // global t base (≡0 mod 4)
#pragma unroll
        for (int tn = 0; tn < 8; ++tn) {
            if (tn < 4) {  // K: h = 16tn+lm
                int h = 16 * tn + lm;
#pragma unroll
                for (int r = 0; r < 4; ++r) {
                    int t = t0 + r;
                    int pc = (h & 7) | ((((h >> 3) ^ (t & 7)) & 7) << 3);
                    Ks[t * 64 + pc] = (bf16)accKV[i][tn][r];
                }
            } else {  // V: h = 16(tn-4)+lm, store transposed [h][t]
                int h = 16 * (tn - 4) + lm;
                int pc = (t0 & 7) | ((((t0 >> 3) ^ (h & 15)) & 15) << 3);
                bf16x4 v4 = {(bf16)accKV[i][tn][0], (bf16)accKV[i][tn][1],
                             (bf16)accKV[i][tn][2], (bf16)accKV[i][tn][3]};
                *(bf16x4*)&Vts[h * 128 + pc] = v4;
            }
        }
    }
#pragma unroll
    for (int tn = 0; tn < 4; ++tn) {  // Q: local rows
        int h = 16 * tn + lm;
#pragma unroll
        for (int r = 0; r < 4; ++r) {
            int lt = 16 * w + quad * 4 + r;
            int pc = (h & 7) | ((((h >> 3) ^ (lt & 7)) & 7) << 3);
            Qh[lt * 64 + pc] = (bf16)accQ[tn][r];
        }
    }
    __syncthreads();

    // ================= Phase 2: attention =================
    const float SCALE = 0.40824829046386307f;  // 6^-0.5
    const int tq = 4 * half + w;   // global q-tile of this wave
    const int lr = 16 * w + lm;    // local q-row (0..63)

    f32x4 sacc[8];
#pragma unroll
    for (int t = 0; t < 8; ++t) sacc[t] = (f32x4){0.f, 0.f, 0.f, 0.f};

    bf16x8 qa[2];
#pragma unroll
    for (int ks = 0; ks < 2; ++ks) {
        int phys = ((ks * 4 + quad) ^ (lr & 7)) & 7;
        qa[ks] = *(const bf16x8*)&Qh[lr * 64 + phys * 8];
    }
#pragma unroll
    for (int tn = 0; tn < 8; ++tn) {
        if (tn <= tq) {
            int nrow = 16 * tn + lm;  // global t
#pragma unroll
            for (int ks = 0; ks < 2; ++ks) {
                int phys = ((ks * 4 + quad) ^ (nrow & 7)) & 7;
                bf16x8 kb = *(const bf16x8*)&Ks[nrow * 64 + phys * 8];
                sacc[tn] = __builtin_amdgcn_mfma_f32_16x16x32_bf16(qa[ks], kb, sacc[tn], 0, 0, 0);
            }
        }
    }

    // softmax without max-pass: |s*SCALE| <~ 35, exp fits fp32
#pragma unroll
    for (int r = 0; r < 4; ++r) {
        int mg = 64 * half + 16 * w + quad * 4 + r;  // global q row
        float sum = 0.f;
#pragma unroll
        for (int tn = 0; tn < 8; ++tn) {
            if (tn <= tq) {
                int n = 16 * tn + lm;
                float e = (n <= mg) ? __expf(sacc[tn][r] * SCALE) : 0.f;
                sacc[tn][r] = e;
                sum += e;
            }
        }
#pragma unroll
        for (int off = 1; off < 16; off <<= 1) sum += __shfl_xor(sum, off, 16);
        float inv = 1.f / sum;
#pragma unroll
        for (int tn = 0; tn < 8; ++tn) {
            if (tn <= tq) sacc[tn][r] *= inv;
        }
    }

    __syncthreads();  // all waves done reading Ks; Ps aliases it

    // write P (own local rows only — no further barrier needed)
#pragma unroll
    for (int tn = 0; tn < 8; ++tn) {
        if (tn <= tq) {
            int n = 16 * tn + lm;
#pragma unroll
            for (int r = 0; r < 4; ++r) {
                int ml = 16 * w + quad * 4 + r;
                int pc = (n & 7) | ((((n >> 3) ^ (ml & 15)) & 15) << 3);
                Ps[ml * 128 + pc] = (bf16)sacc[tn][r];
            }
        }
    }
    if ((tq & 1) == 0) {  // zero half-covered k-tile
        int ml = 16 * w + lm;
        int c0 = 16 * (tq + 1) + quad * 4;
        int pc = (c0 & 7) | ((((c0 >> 3) ^ (ml & 15)) & 15) << 3);
        *(bf16x4*)&Ps[ml * 128 + pc] = (bf16x4){(bf16)0.f, (bf16)0.f, (bf16)0.f, (bf16)0.f};
    }

    // O = P @ V
    f32x4 oacc[4];
#pragma unroll
    for (int t = 0; t < 4; ++t) oacc[t] = (f32x4){0.f, 0.f, 0.f, 0.f};

    const int nks = (tq + 2) >> 1;  // wave-uniform
    for (int ks = 0; ks < nks; ++ks) {
        int unit = ks * 4 + quad;
        int physP = (unit ^ (lr & 15)) & 15;
        bf16x8 pa = *(const bf16x8*)&Ps[lr * 128 + physP * 8];
#pragma unroll
        for (int th = 0; th < 4; ++th) {
            int hrow = 16 * th + lm;
            int ph2 = (unit ^ (hrow & 15)) & 15;
            bf16x8 vb = *(const bf16x8*)&Vts[hrow * 128 + ph2 * 8];
            oacc[th] = __builtin_amdgcn_mfma_f32_16x16x32_bf16(pa, vb, oacc[th], 0, 0, 0);
        }
    }

    // store O fp32: out[b][64*half + ml][h]
    float* ob = out + (size_t)b * (T_ * H_) + half * 64 * H_;
#pragma unroll
    for (int th = 0; th < 4; ++th) {
        int h = 16 * th + lm;
#pragma unroll
        for (int r = 0; r < 4; ++r) {
            int ml = 16 * w + quad * 4 + r;
            ob[ml * 64 + h] = oacc[th][r];
        }
    }
}

extern "C" void kernel_launch(void* const* d_in, const int* in_sizes, int n_in,
                              void* d_out, int out_size, void* d_ws, size_t ws_size,
                              hipStream_t stream) {
    const float* x  = (const float*)d_in[0];
    const float* Wq = (const float*)d_in[1];
    const float* Wk = (const float*)d_in[2];
    const float* Wv = (const float*)d_in[3];
    float* o = (float*)d_out;
    bf16* Wt = (bf16*)d_ws;   // 192*384*2 = 147456 B
    wt_conv<<<dim3(36), dim3(256), 0, stream>>>(Wq, Wk, Wv, Wt);
    head_fused<<<dim3(2 * B_), dim3(256), 0, stream>>>(x, Wt, o);
}